// Round 1
// baseline (50043.427 us; speedup 1.0000x reference)
//
#include <hip/hip_runtime.h>
#include <math.h>

#define B_ 128
#define T_ 128
#define IN_ 75
#define H_ 512
#define C_ 60
#define Q_ 25

// ---- workspace layout (floats) ----
#define OFF_WG4T 0
#define OFF_WG4S (512*512*4)
#define OFF_WG41 (2*512*512*4)
#define OFF_WI4T (3*512*512*4)
#define OFF_WI4S (OFF_WI4T + 75*512*4)
#define OFF_WI41 (OFF_WI4S + 75*512*4)
#define OFF_WXH  (OFF_WI41 + 75*512*4)
#define OFF_UP   (OFF_WXH + 512*512*4)
#define OFF_FC2P (OFF_UP + 512*512)
#define WS_FLOATS (OFF_FC2P + 75*512*2)

__device__ __forceinline__ float sigm(float v) { return 1.f / (1.f + expf(-v)); }

// Pack weights into coalesced-per-j, gate-interleaved layouts.
__global__ void prep_kernel(const float* __restrict__ Whh_t, const float* __restrict__ Whh_s,
                            const float* __restrict__ Whh_1,
                            const float* __restrict__ Wih_t, const float* __restrict__ Wih_s,
                            const float* __restrict__ Wih_1,
                            const float* __restrict__ W_x_t, const float* __restrict__ W_h_t,
                            const float* __restrict__ W_x_s, const float* __restrict__ W_h_s,
                            const float* __restrict__ U_s,
                            const float* __restrict__ fct_w, const float* __restrict__ fc1_w,
                            float* __restrict__ ws) {
  const int idx0 = blockIdx.x * blockDim.x + threadIdx.x;
  const int stride = gridDim.x * blockDim.x;

  // Whh transposes: WG4[k][j][g] = Whh[g*512+j][k]
  for (int i = idx0; i < 2048 * 128; i += stride) {
    const int row = i >> 7;       // g*512+j
    const int k4 = i & 127;
    const int g = row >> 9, j = row & 511;
    const float4 vt = *reinterpret_cast<const float4*>(&Whh_t[row * 512 + k4 * 4]);
    const float4 vs = *reinterpret_cast<const float4*>(&Whh_s[row * 512 + k4 * 4]);
    const float4 v1 = *reinterpret_cast<const float4*>(&Whh_1[row * 512 + k4 * 4]);
#pragma unroll
    for (int u = 0; u < 4; ++u) {
      const int k = k4 * 4 + u;
      ws[OFF_WG4T + ((k * 512 + j) << 2) + g] = (&vt.x)[u];
      ws[OFF_WG4S + ((k * 512 + j) << 2) + g] = (&vs.x)[u];
      ws[OFF_WG41 + ((k * 512 + j) << 2) + g] = (&v1.x)[u];
    }
  }
  // Wih transposes: WI4[k][j][g] = Wih[g*512+j][k]
  for (int i = idx0; i < 2048 * 75; i += stride) {
    const int row = i / 75, k = i - row * 75;
    const int g = row >> 9, j = row & 511;
    ws[OFF_WI4T + ((k * 512 + j) << 2) + g] = Wih_t[i];
    ws[OFF_WI4S + ((k * 512 + j) << 2) + g] = Wih_s[i];
    ws[OFF_WI41 + ((k * 512 + j) << 2) + g] = Wih_1[i];
  }
  // WXH[k][j] = (W_x_t, W_h_t, W_x_s, W_h_s)[k][j]; UP[k/4][j][k%4] = U_s[k][j]
  for (int i = idx0; i < 512 * 512; i += stride) {
    const int k = i >> 9, j = i & 511;
    float4 v;
    v.x = W_x_t[i]; v.y = W_h_t[i]; v.z = W_x_s[i]; v.w = W_h_s[i];
    *reinterpret_cast<float4*>(&ws[OFF_WXH + (i << 2)]) = v;
    ws[OFF_UP + (((k >> 2) * 512 + j) << 2) + (k & 3)] = U_s[i];
  }
  // FC2P[k][j] = (fct_w[j][k], fc1_w[j][k])
  for (int i = idx0; i < 75 * 512; i += stride) {
    const int k = i >> 9, j = i & 511;
    float2 v;
    v.x = fct_w[j * 75 + k];
    v.y = fc1_w[j * 75 + k];
    *reinterpret_cast<float2*>(&ws[OFF_FC2P + (i << 1)]) = v;
  }
}

#define PH2_STEP(u, HT, HS, H1V, T1V, T2V) do { \
    const float4 wt = WG4T[((kk + u) << 9) + tid]; \
    gt0 = fmaf(HT, wt.x, gt0); gt1 = fmaf(HT, wt.y, gt1); \
    gt2 = fmaf(HT, wt.z, gt2); gt3 = fmaf(HT, wt.w, gt3); \
    const float4 wv = WG4S[((kk + u) << 9) + tid]; \
    gs0 = fmaf(HS, wv.x, gs0); gs1 = fmaf(HS, wv.y, gs1); \
    gs2 = fmaf(HS, wv.z, gs2); gs3 = fmaf(HS, wv.w, gs3); \
    const float4 w1 = WG41[((kk + u) << 9) + tid]; \
    g10 = fmaf(H1V, w1.x, g10); g11 = fmaf(H1V, w1.y, g11); \
    g12 = fmaf(H1V, w1.z, g12); g13 = fmaf(H1V, w1.w, g13); \
    const float4 wx = WXH4[((kk + u) << 9) + tid]; \
    accB = fmaf(T1V, wx.x, accB); accB = fmaf(HT, wx.y, accB); \
    accS = fmaf(T2V, wx.z, accS); accS = fmaf(HS, wx.w, accS); \
  } while (0)

__global__ __launch_bounds__(512)
void scan_kernel(const float* __restrict__ inputs, const float* __restrict__ ws,
                 const float* __restrict__ bih_t, const float* __restrict__ bhh_t,
                 const float* __restrict__ bih_s, const float* __restrict__ bhh_s,
                 const float* __restrict__ bih_1, const float* __restrict__ bhh_1,
                 const float* __restrict__ fct_b, const float* __restrict__ fc1_b,
                 const float* __restrict__ fc2_w, const float* __restrict__ fc2_b,
                 const float* __restrict__ b_t, const float* __restrict__ b_s,
                 const float* __restrict__ b_us,
                 const float* __restrict__ fc_w, const float* __restrict__ fc_b,
                 float* __restrict__ out) {
  const int b = blockIdx.x;
  const int tid = threadIdx.x;

  const float4* __restrict__ WG4T = reinterpret_cast<const float4*>(ws + OFF_WG4T);
  const float4* __restrict__ WG4S = reinterpret_cast<const float4*>(ws + OFF_WG4S);
  const float4* __restrict__ WG41 = reinterpret_cast<const float4*>(ws + OFF_WG41);
  const float4* __restrict__ WI4T = reinterpret_cast<const float4*>(ws + OFF_WI4T);
  const float4* __restrict__ WI4S = reinterpret_cast<const float4*>(ws + OFF_WI4S);
  const float4* __restrict__ WI41 = reinterpret_cast<const float4*>(ws + OFF_WI41);
  const float4* __restrict__ WXH4 = reinterpret_cast<const float4*>(ws + OFF_WXH);
  const float4* __restrict__ UP4  = reinterpret_cast<const float4*>(ws + OFF_UP);
  const float2* __restrict__ FC2P = reinterpret_cast<const float2*>(ws + OFF_FC2P);

  __shared__ alignas(16) float h_t[H_], h_s[H_], h1[H_];
  __shared__ alignas(16) float tmp1[H_], tmp2[H_], st_a[H_], st2[H_];
  __shared__ float xsh[IN_ + 1], xg[IN_ + 1];
  __shared__ float qv[Q_], alpha[Q_];
  __shared__ float lg[C_];

  // hoisted biases (thread j = tid owns hidden unit tid)
  const float bt0 = bih_t[tid] + bhh_t[tid];
  const float bt1 = bih_t[H_ + tid] + bhh_t[H_ + tid];
  const float bt2 = bih_t[2 * H_ + tid] + bhh_t[2 * H_ + tid];
  const float bt3 = bih_t[3 * H_ + tid] + bhh_t[3 * H_ + tid];
  const float bs0 = bih_s[tid] + bhh_s[tid];
  const float bs1 = bih_s[H_ + tid] + bhh_s[H_ + tid];
  const float bs2 = bih_s[2 * H_ + tid] + bhh_s[2 * H_ + tid];
  const float bs3 = bih_s[3 * H_ + tid] + bhh_s[3 * H_ + tid];
  const float b10 = bih_1[tid] + bhh_1[tid];
  const float b11 = bih_1[H_ + tid] + bhh_1[H_ + tid];
  const float b12 = bih_1[2 * H_ + tid] + bhh_1[2 * H_ + tid];
  const float b13 = bih_1[3 * H_ + tid] + bhh_1[3 * H_ + tid];
  const float bsv = b_s[tid];
  const float bBeta = bsv + b_t[tid];
  const float bus_r = b_us[tid];
  const float fctb_r = fct_b[tid];
  const float fc1b_r = fc1_b[tid];

  float c_t = 0.f, c_s = 0.f, c1 = 0.f;
  h_t[tid] = 0.f; h_s[tid] = 0.f; h1[tid] = 0.f;

  float* out_logp = out;
  float* out_alpha = out + B_ * C_;
  float* out_beta = out + B_ * C_ + T_ * B_ * Q_;

  const float* xrow = inputs + (size_t)b * T_ * IN_;

  for (int t = 0; t < T_; ++t) {
    __syncthreads();                       // make prev-iter state writes visible; protect xsh
    if (tid < IN_) xsh[tid] = xrow[t * IN_ + tid];
    __syncthreads();

    // phase 1: tmp1 = x@fct_w.T + fct_b ; tmp2 = x@fc1_w.T + fc1_b
    float a1 = fctb_r, a2 = fc1b_r;
    for (int k = 0; k < IN_; ++k) {
      const float xv = xsh[k];
      const float2 fv = FC2P[(k << 9) + tid];
      a1 = fmaf(xv, fv.x, a1);
      a2 = fmaf(xv, fv.y, a2);
    }
    tmp1[tid] = a1; tmp2[tid] = a2;
    __syncthreads();

    // phase 2: all dots against OLD states
    float gt0 = bt0, gt1 = bt1, gt2 = bt2, gt3 = bt3;
    float gs0 = bs0, gs1 = bs1, gs2 = bs2, gs3 = bs3;
    float g10 = b10, g11 = b11, g12 = b12, g13 = b13;
    float accB = bBeta, accS = bsv;

    for (int k = 0; k < IN_; ++k) {
      const float xv = xsh[k];
      const float4 wt = WI4T[(k << 9) + tid];
      gt0 = fmaf(xv, wt.x, gt0); gt1 = fmaf(xv, wt.y, gt1);
      gt2 = fmaf(xv, wt.z, gt2); gt3 = fmaf(xv, wt.w, gt3);
      const float4 wv = WI4S[(k << 9) + tid];
      gs0 = fmaf(xv, wv.x, gs0); gs1 = fmaf(xv, wv.y, gs1);
      gs2 = fmaf(xv, wv.z, gs2); gs3 = fmaf(xv, wv.w, gs3);
    }
    for (int kk = 0; kk < H_; kk += 4) {
      const float4 ht4 = *reinterpret_cast<const float4*>(&h_t[kk]);
      const float4 hs4 = *reinterpret_cast<const float4*>(&h_s[kk]);
      const float4 h14 = *reinterpret_cast<const float4*>(&h1[kk]);
      const float4 t14 = *reinterpret_cast<const float4*>(&tmp1[kk]);
      const float4 t24 = *reinterpret_cast<const float4*>(&tmp2[kk]);
      PH2_STEP(0, ht4.x, hs4.x, h14.x, t14.x, t24.x);
      PH2_STEP(1, ht4.y, hs4.y, h14.y, t14.y, t24.y);
      PH2_STEP(2, ht4.z, hs4.z, h14.z, t14.z, t24.z);
      PH2_STEP(3, ht4.w, hs4.w, h14.w, t14.w, t24.w);
    }

    const float stv = tanhf(accS);
    const float betav = fmaxf(accB, 0.f);
    const float ctn = sigm(gt1) * c_t + sigm(gt0) * tanhf(gt2);
    const float htn = sigm(gt3) * tanhf(ctn);
    const float csn = sigm(gs1) * c_s + sigm(gs0) * tanhf(gs2);
    const float hsn = sigm(gs3) * tanhf(csn);
    st_a[tid] = stv;
    __syncthreads();                       // A: all reads of old state done
    h_t[tid] = htn; c_t = ctn;
    h_s[tid] = hsn; c_s = csn;

    // phase 3: st2 = st @ U_s + b_us
    float a3 = bus_r;
    for (int k4 = 0; k4 < H_ / 4; ++k4) {
      const float4 sv = *reinterpret_cast<const float4*>(&st_a[k4 << 2]);
      const float4 uv = UP4[(k4 << 9) + tid];
      a3 = fmaf(sv.x, uv.x, a3); a3 = fmaf(sv.y, uv.y, a3);
      a3 = fmaf(sv.z, uv.z, a3); a3 = fmaf(sv.w, uv.w, a3);
    }
    st2[tid] = a3;
    __syncthreads();                       // B

    // phase 4a: q = st2 @ fc2_w.T + fc2_b
    if (tid < Q_) {
      float aq = fc2_b[tid];
      const float* fr = fc2_w + tid * H_;
      for (int k = 0; k < H_; k += 4) {
        const float4 sv = *reinterpret_cast<const float4*>(&st2[k]);
        const float4 fv = *reinterpret_cast<const float4*>(&fr[k]);
        aq += sv.x * fv.x + sv.y * fv.y + sv.z * fv.z + sv.w * fv.w;
      }
      qv[tid] = aq;
    }
    __syncthreads();                       // C
    // phase 4b: alpha = softmax(q)
    if (tid < Q_) {
      float m = qv[0];
      for (int i = 1; i < Q_; ++i) m = fmaxf(m, qv[i]);
      float s = 0.f;
      for (int i = 0; i < Q_; ++i) s += expf(qv[i] - m);
      const float al = expf(qv[tid] - m) / s;
      alpha[tid] = al;
      out_alpha[(t * B_ + b) * Q_ + tid] = al;
    }
    __syncthreads();                       // D
    if (tid < IN_) xg[tid] = xsh[tid] * alpha[tid / 3];
    __syncthreads();                       // E

    // phase 5: cell1 on x_gated (h-part already in g1*)
    for (int k = 0; k < IN_; ++k) {
      const float xv = xg[k];
      const float4 w1 = WI41[(k << 9) + tid];
      g10 = fmaf(xv, w1.x, g10); g11 = fmaf(xv, w1.y, g11);
      g12 = fmaf(xv, w1.z, g12); g13 = fmaf(xv, w1.w, g13);
    }
    const float c1n = sigm(g11) * c1 + sigm(g10) * tanhf(g12);
    const float h1raw = sigm(g13) * tanhf(c1n);
    c1 = c1n;
    const float h1g = h1raw * betav;       // torch aliasing bug: gated value is carried
    h1[tid] = h1g;
    out_beta[(size_t)(t * B_ + b) * H_ + tid] = betav;
  }
  __syncthreads();

  // logits + log_softmax from final gated h1
  if (tid < C_) {
    float al = fc_b[tid];
    const float* fr = fc_w + tid * H_;
    for (int k = 0; k < H_; k += 4) {
      const float4 hv = *reinterpret_cast<const float4*>(&h1[k]);
      const float4 fv = *reinterpret_cast<const float4*>(&fr[k]);
      al += hv.x * fv.x + hv.y * fv.y + hv.z * fv.z + hv.w * fv.w;
    }
    lg[tid] = al;
  }
  __syncthreads();
  if (tid < C_) {
    float m = lg[0];
    for (int i = 1; i < C_; ++i) m = fmaxf(m, lg[i]);
    float s = 0.f;
    for (int i = 0; i < C_; ++i) s += expf(lg[i] - m);
    out_logp[b * C_ + tid] = lg[tid] - m - logf(s);
  }
}

extern "C" void kernel_launch(void* const* d_in, const int* in_sizes, int n_in,
                              void* d_out, int out_size, void* d_ws, size_t ws_size,
                              hipStream_t stream) {
  const float* inputs = (const float*)d_in[0];
  const float* Wih_t = (const float*)d_in[2];
  const float* Whh_t = (const float*)d_in[3];
  const float* bih_t = (const float*)d_in[4];
  const float* bhh_t = (const float*)d_in[5];
  const float* Wih_s = (const float*)d_in[6];
  const float* Whh_s = (const float*)d_in[7];
  const float* bih_s = (const float*)d_in[8];
  const float* bhh_s = (const float*)d_in[9];
  const float* Wih_1 = (const float*)d_in[10];
  const float* Whh_1 = (const float*)d_in[11];
  const float* bih_1 = (const float*)d_in[12];
  const float* bhh_1 = (const float*)d_in[13];
  const float* fc_w = (const float*)d_in[14];
  const float* fc_b = (const float*)d_in[15];
  const float* fct_w = (const float*)d_in[16];
  const float* fct_b = (const float*)d_in[17];
  const float* fc1_w = (const float*)d_in[18];
  const float* fc1_b = (const float*)d_in[19];
  const float* fc2_w = (const float*)d_in[20];
  const float* fc2_b = (const float*)d_in[21];
  const float* W_x_t = (const float*)d_in[22];
  const float* W_h_t = (const float*)d_in[23];
  const float* b_t   = (const float*)d_in[24];
  const float* W_x_s = (const float*)d_in[25];
  const float* W_h_s = (const float*)d_in[26];
  const float* U_s   = (const float*)d_in[27];
  const float* b_s   = (const float*)d_in[28];
  const float* b_us  = (const float*)d_in[29];

  if (ws_size < (size_t)WS_FLOATS * sizeof(float)) return;  // fail loudly (output stays poisoned)

  float* ws = (float*)d_ws;
  float* out = (float*)d_out;

  hipLaunchKernelGGL(prep_kernel, dim3(1024), dim3(256), 0, stream,
                     Whh_t, Whh_s, Whh_1, Wih_t, Wih_s, Wih_1,
                     W_x_t, W_h_t, W_x_s, W_h_s, U_s, fct_w, fc1_w, ws);
  hipLaunchKernelGGL(scan_kernel, dim3(B_), dim3(H_), 0, stream,
                     inputs, ws, bih_t, bhh_t, bih_s, bhh_s, bih_1, bhh_1,
                     fct_b, fc1_b, fc2_w, fc2_b, b_t, b_s, b_us, fc_w, fc_b, out);
}

// Round 2
// 30890.244 us; speedup vs baseline: 1.6200x; 1.6200x over previous
//
#include <hip/hip_runtime.h>
#include <hip/hip_cooperative_groups.h>
#include <math.h>

namespace cg = cooperative_groups;

#define B_ 128
#define T_ 128
#define IN_ 75
#define H_ 512
#define C_ 60
#define Q_ 25

// ---------------- workspace layout (bytes) ----------------
constexpr size_t OFF_WHHP = 0;                               // float4 [(cell*512+u)*512+k] : {g0,g1,g2,g3}
constexpr size_t SZ_WHHP  = (size_t)3*512*512*16;
constexpr size_t OFF_SP   = OFF_WHHP + SZ_WHHP;              // float4 [buf][k][b] : {h_t,h_s,tmp1,tmp2}
constexpr size_t SZ_SP    = (size_t)2*512*128*16;
constexpr size_t OFF_H1   = OFF_SP + SZ_SP;                  // float  [k][b]
constexpr size_t SZ_H1    = (size_t)512*128*4;
constexpr size_t OFF_BETA = OFF_H1 + SZ_H1;                  // float  [b][j]
constexpr size_t SZ_BETA  = (size_t)128*512*4;
constexpr size_t OFF_ST   = OFF_BETA + SZ_BETA;              // float  [b][j]
constexpr size_t SZ_ST    = SZ_BETA;
constexpr size_t OFF_U2   = OFF_ST + SZ_ST;                  // float  [qi][j]  (U_s @ fc2_w.T folded)
constexpr size_t SZ_U2    = (size_t)25*512*4;
constexpr size_t OFF_B2   = OFF_U2 + SZ_U2;                  // float  [32]
constexpr size_t SZ_B2    = 128;
constexpr size_t OFF_WXT  = OFF_B2 + SZ_B2;                  // ushort4 [u][k] : bf16 {W_x_t,W_h_t,W_x_s,W_h_s}
constexpr size_t SZ_WXT   = (size_t)512*512*8;
constexpr size_t OFF_WIHP = OFF_WXT + SZ_WXT;                // ushort4 [(c*512+u)*75+k] : bf16 gates
constexpr size_t SZ_WIHP  = (size_t)2*512*75*8;
constexpr size_t OFF_FT2  = OFF_WIHP + SZ_WIHP;              // ushort2 [u][k] : bf16 {fct_w,fc1_w}
constexpr size_t SZ_FT2   = (size_t)512*75*4;
constexpr size_t OFF_W1T  = OFF_FT2 + SZ_FT2;                // ushort4 [k][j] : bf16 Wih_1 gates
constexpr size_t SZ_W1T   = (size_t)75*512*8;
constexpr size_t OFF_G1H  = OFF_W1T + SZ_W1T;                // ushort4 [b][j] : bf16 gates1 h-part + bias
constexpr size_t SZ_G1H   = (size_t)128*512*8;
constexpr size_t WS_BYTES = OFF_G1H + SZ_G1H;                // = 19,214,464 (< known-safe ~20 MB)

struct Full {
  const float* inputs;
  const float* Wih_t; const float* Whh_t; const float* bih_t; const float* bhh_t;
  const float* Wih_s; const float* Whh_s; const float* bih_s; const float* bhh_s;
  const float* Wih_1; const float* Whh_1; const float* bih_1; const float* bhh_1;
  const float* fc_w;  const float* fc_b;
  const float* fct_w; const float* fct_b;
  const float* fc1_w; const float* fc1_b;
  const float* fc2_w; const float* fc2_b;
  const float* W_x_t; const float* W_h_t; const float* b_t;
  const float* W_x_s; const float* W_h_s; const float* U_s; const float* b_s; const float* b_us;
  char* ws; float* out;
};

__device__ __forceinline__ float sigm(float v) { return 1.f / (1.f + expf(-v)); }
__device__ __forceinline__ float bfu(unsigned short h) { return __uint_as_float((unsigned)h << 16); }
__device__ __forceinline__ unsigned short tob(float f) {
  unsigned u = __float_as_uint(f);
  return (unsigned short)((u + 0x7fffu + ((u >> 16) & 1u)) >> 16);
}

// ---------------- prep: pack weights into ws ----------------
__global__ void prep_pack(Full f) {
  const size_t N1 = (size_t)3*512*512;       // WhhP
  const size_t N2 = (size_t)512*512;         // WXT
  const size_t N3 = (size_t)2*512*75;        // WIHP
  const size_t N4 = (size_t)512*75;          // FT2
  const size_t N5 = (size_t)512*75;          // W1T
  const size_t N6 = (size_t)25*512;          // U2
  const size_t N7 = 25;                      // b2
  const size_t TOT = N1+N2+N3+N4+N5+N6+N7;
  float4*  WHHP = (float4*)(f.ws + OFF_WHHP);
  ushort4* WXT  = (ushort4*)(f.ws + OFF_WXT);
  ushort4* WIHP = (ushort4*)(f.ws + OFF_WIHP);
  ushort2* FT2  = (ushort2*)(f.ws + OFF_FT2);
  ushort4* W1T  = (ushort4*)(f.ws + OFF_W1T);
  float*   U2   = (float*)(f.ws + OFF_U2);
  float*   B2   = (float*)(f.ws + OFF_B2);
  for (size_t i = (size_t)blockIdx.x*blockDim.x + threadIdx.x; i < TOT;
       i += (size_t)gridDim.x*blockDim.x) {
    if (i < N1) {
      size_t c = i >> 18, r = i & 262143, u = r >> 9, k = r & 511;
      const float* W = (c == 0) ? f.Whh_t : (c == 1) ? f.Whh_s : f.Whh_1;
      WHHP[(c*512+u)*512 + k] = make_float4(
          W[u*512+k], W[(512+u)*512+k], W[(1024+u)*512+k], W[(1536+u)*512+k]);
    } else if (i < N1+N2) {
      size_t j = i - N1; size_t k = j >> 9, u = j & 511;
      ushort4 v; v.x = tob(f.W_x_t[k*512+u]); v.y = tob(f.W_h_t[k*512+u]);
      v.z = tob(f.W_x_s[k*512+u]); v.w = tob(f.W_h_s[k*512+u]);
      WXT[u*512 + k] = v;
    } else if (i < N1+N2+N3) {
      size_t j = i - N1 - N2; size_t c = j / 38400, r = j % 38400, u = r / 75, k = r % 75;
      const float* W = c ? f.Wih_s : f.Wih_t;
      ushort4 v; v.x = tob(W[u*75+k]); v.y = tob(W[(512+u)*75+k]);
      v.z = tob(W[(1024+u)*75+k]); v.w = tob(W[(1536+u)*75+k]);
      WIHP[(c*512+u)*75 + k] = v;
    } else if (i < N1+N2+N3+N4) {
      size_t j = i - N1 - N2 - N3; size_t u = j / 75, k = j % 75;
      ushort2 v; v.x = tob(f.fct_w[u*75+k]); v.y = tob(f.fc1_w[u*75+k]);
      FT2[u*75 + k] = v;
    } else if (i < N1+N2+N3+N4+N5) {
      size_t j = i - N1 - N2 - N3 - N4; size_t jj = j / 75, k = j % 75;
      ushort4 v; v.x = tob(f.Wih_1[jj*75+k]); v.y = tob(f.Wih_1[(512+jj)*75+k]);
      v.z = tob(f.Wih_1[(1024+jj)*75+k]); v.w = tob(f.Wih_1[(1536+jj)*75+k]);
      W1T[k*512 + jj] = v;
    } else if (i < N1+N2+N3+N4+N5+N6) {
      size_t j = i - N1 - N2 - N3 - N4 - N5; size_t qi = j >> 9, col = j & 511;
      float acc = 0.f;
      for (int n = 0; n < 512; ++n) acc = fmaf(f.U_s[col*512+n], f.fc2_w[qi*512+n], acc);
      U2[qi*512 + col] = acc;
    } else {
      size_t qi = i - N1 - N2 - N3 - N4 - N5 - N6;
      float acc = f.fc2_b[qi];
      for (int n = 0; n < 512; ++n) acc = fmaf(f.b_us[n], f.fc2_w[qi*512+n], acc);
      B2[qi] = acc;
    }
  }
}

// ---------------- prep: initial state (SP buf0, h1=0) ----------------
__global__ __launch_bounds__(512) void prep_state(Full f) {
  const int b = blockIdx.x, j = threadIdx.x;
  __shared__ float x0[77];
  if (j < IN_) x0[j] = f.inputs[(size_t)b*T_*IN_ + j];
  __syncthreads();
  float t1 = f.fct_b[j], t2 = f.fc1_b[j];
  for (int k = 0; k < IN_; ++k) {
    t1 = fmaf(x0[k], f.fct_w[j*IN_+k], t1);
    t2 = fmaf(x0[k], f.fc1_w[j*IN_+k], t2);
  }
  float4* SP = (float4*)(f.ws + OFF_SP);
  SP[(size_t)j*128 + b] = make_float4(0.f, 0.f, t1, t2);
  ((float*)(f.ws + OFF_H1))[(size_t)j*128 + b] = 0.f;
}

// ---------------- main cooperative scan ----------------
__global__ __launch_bounds__(512) void scan2(Full f) {
  cg::grid_group grid = cg::this_grid();
  const int tid = threadIdx.x, bid = blockIdx.x;
  const int bj = bid & 63, bb = bid >> 6;
  const int half = tid >> 8, rest = tid & 255;
  const int u = rest >> 5, bL = rest & 31;
  const int ug = bj*8 + u;            // global unit this thread accumulates
  const int bg = bb*32 + bL;          // global row this thread accumulates
  const int k0 = half * 256;
  const int kx0 = half ? 38 : 0, kx1 = half ? 75 : 38;

  char* wsb = f.ws;
  const float4*  WHHP = (const float4*)(wsb + OFF_WHHP);
  const ushort4* WXT  = (const ushort4*)(wsb + OFF_WXT);
  const ushort4* WIHP = (const ushort4*)(wsb + OFF_WIHP);
  const ushort2* FT2  = (const ushort2*)(wsb + OFF_FT2);
  const ushort4* W1T  = (const ushort4*)(wsb + OFF_W1T);
  float4*  SP   = (float4*)(wsb + OFF_SP);
  float*   H1   = (float*)(wsb + OFF_H1);
  float*   BETA = (float*)(wsb + OFF_BETA);
  float*   ST   = (float*)(wsb + OFF_ST);
  const float* U2 = (const float*)(wsb + OFF_U2);
  const float* B2 = (const float*)(wsb + OFF_B2);
  ushort4* G1H  = (ushort4*)(wsb + OFF_G1H);

  float* out_logp  = f.out;
  float* out_alpha = f.out + B_*C_;
  float* out_beta  = f.out + B_*C_ + (size_t)T_*B_*Q_;

  __shared__ float red[256][17];
  __shared__ float xcur[32][77], xnext[32][77];
  __shared__ float st_l[2][512];
  __shared__ float qp[2][25][8];
  __shared__ float qv[2][25];
  __shared__ float al2[2][25];
  __shared__ float xg_l[2][77];
  __shared__ float h1l[2][512];
  __shared__ float lgp[2][60][4];
  __shared__ float lg[2][60];

  // biases
  float btb[4], bsb[4], b1b[4];
#pragma unroll
  for (int g = 0; g < 4; ++g) {
    btb[g] = f.bih_t[g*512+ug] + f.bhh_t[g*512+ug];
    bsb[g] = f.bih_s[g*512+ug] + f.bhh_s[g*512+ug];
    b1b[g] = f.bih_1[g*512+ug] + f.bhh_1[g*512+ug];
  }
  const float bB = f.b_s[ug] + f.b_t[ug];
  const float bS = f.b_s[ug];
  const float bT1 = f.fct_b[ug], bT2 = f.fc1_b[ug];

  float c_t = 0.f, c_s = 0.f;     // valid in half==0 threads
  float c1a = 0.f, c1b = 0.f;     // valid in blocks < 64 (S2 threads)

  const float4* whT = WHHP + (size_t)ug*512;
  const float4* whS = WHHP + (size_t)(512+ug)*512;
  const float4* wh1 = WHHP + (size_t)(1024+ug)*512;
  const ushort4* wxp = WXT + (size_t)ug*512;
  const ushort4* wiT = WIHP + (size_t)ug*75;
  const ushort4* wiS = WIHP + (size_t)(512+ug)*75;
  const ushort2* ftp = FT2 + (size_t)ug*75;

  for (int t = 0; t < T_; ++t) {
    const int cur = t & 1;
    // stage x rows for this block's b-slice
    for (int i = tid; i < 32*IN_; i += 512) {
      int b = i / IN_, k = i - b*IN_;
      size_t base = (size_t)(bb*32 + b)*T_*IN_ + (size_t)t*IN_;
      xcur[b][k] = f.inputs[base + k];
      if (t < T_-1) xnext[b][k] = f.inputs[base + IN_ + k];
    }
    __syncthreads();

    float a0=0,a1=0,a2=0,a3=0,a4=0,a5=0,a6=0,a7=0,a8=0,a9=0,a10=0,a11=0,a12=0,a13=0,a14=0,a15=0;
    const float4* spc = SP + (size_t)cur*512*128;
#pragma unroll 4
    for (int k = k0; k < k0 + 256; ++k) {
      float4 s4 = spc[(size_t)k*128 + bg];       // {h_t,h_s,tmp1,tmp2} (prev step)
      float h1v = H1[(size_t)k*128 + bg];        // prev gated h1
      float4 wt = whT[k], wsv = whS[k], w1 = wh1[k];
      ushort4 wxu = wxp[k];
      a0 = fmaf(s4.x, wt.x, a0);  a1 = fmaf(s4.x, wt.y, a1);
      a2 = fmaf(s4.x, wt.z, a2);  a3 = fmaf(s4.x, wt.w, a3);
      a4 = fmaf(s4.y, wsv.x, a4); a5 = fmaf(s4.y, wsv.y, a5);
      a6 = fmaf(s4.y, wsv.z, a6); a7 = fmaf(s4.y, wsv.w, a7);
      a8 = fmaf(h1v, w1.x, a8);   a9 = fmaf(h1v, w1.y, a9);
      a10 = fmaf(h1v, w1.z, a10); a11 = fmaf(h1v, w1.w, a11);
      a12 = fmaf(s4.z, bfu(wxu.x), a12); a12 = fmaf(s4.x, bfu(wxu.y), a12);
      a13 = fmaf(s4.w, bfu(wxu.z), a13); a13 = fmaf(s4.y, bfu(wxu.w), a13);
    }
    for (int k = kx0; k < kx1; ++k) {
      float xv = xcur[bL][k];
      ushort4 wa = wiT[k], wb = wiS[k];
      a0 = fmaf(xv, bfu(wa.x), a0); a1 = fmaf(xv, bfu(wa.y), a1);
      a2 = fmaf(xv, bfu(wa.z), a2); a3 = fmaf(xv, bfu(wa.w), a3);
      a4 = fmaf(xv, bfu(wb.x), a4); a5 = fmaf(xv, bfu(wb.y), a5);
      a6 = fmaf(xv, bfu(wb.z), a6); a7 = fmaf(xv, bfu(wb.w), a7);
    }
    if (t < T_-1) {
      for (int k = kx0; k < kx1; ++k) {
        float xn = xnext[bL][k];
        ushort2 f2 = ftp[k];
        a14 = fmaf(xn, bfu(f2.x), a14); a15 = fmaf(xn, bfu(f2.y), a15);
      }
    }

    if (half) {
      red[rest][0]=a0; red[rest][1]=a1; red[rest][2]=a2; red[rest][3]=a3;
      red[rest][4]=a4; red[rest][5]=a5; red[rest][6]=a6; red[rest][7]=a7;
      red[rest][8]=a8; red[rest][9]=a9; red[rest][10]=a10; red[rest][11]=a11;
      red[rest][12]=a12; red[rest][13]=a13; red[rest][14]=a14; red[rest][15]=a15;
    }
    __syncthreads();
    if (!half) {
      a0+=red[rest][0]; a1+=red[rest][1]; a2+=red[rest][2]; a3+=red[rest][3];
      a4+=red[rest][4]; a5+=red[rest][5]; a6+=red[rest][6]; a7+=red[rest][7];
      a8+=red[rest][8]; a9+=red[rest][9]; a10+=red[rest][10]; a11+=red[rest][11];
      a12+=red[rest][12]; a13+=red[rest][13]; a14+=red[rest][14]; a15+=red[rest][15];

      float it = sigm(a0+btb[0]), ft = sigm(a1+btb[1]);
      float gt = tanhf(a2+btb[2]), ot = sigm(a3+btb[3]);
      c_t = ft*c_t + it*gt;
      float htn = ot*tanhf(c_t);
      float is = sigm(a4+bsb[0]), fs = sigm(a5+bsb[1]);
      float gs = tanhf(a6+bsb[2]), os = sigm(a7+bsb[3]);
      c_s = fs*c_s + is*gs;
      float hsn = os*tanhf(c_s);
      float stv = tanhf(a13 + bS);
      float betav = fmaxf(a12 + bB, 0.f);
      float t1n = a14 + bT1, t2n = a15 + bT2;

      SP[(size_t)(cur^1)*512*128 + (size_t)ug*128 + bg] = make_float4(htn, hsn, t1n, t2n);
      ushort4 gv; gv.x = tob(a8+b1b[0]); gv.y = tob(a9+b1b[1]);
      gv.z = tob(a10+b1b[2]); gv.w = tob(a11+b1b[3]);
      G1H[(size_t)bg*512 + ug] = gv;
      BETA[(size_t)bg*512 + ug] = betav;
      ST[(size_t)bg*512 + ug] = stv;
    }
    __threadfence();
    grid.sync();

    // ---- S2: rows finishing (q, softmax, x_gated, cell1, h1*beta) ----
    if (bid < 64) {
      const int r0 = 2*bid, r1 = r0 + 1;
      st_l[0][tid] = ST[(size_t)r0*512 + tid];
      st_l[1][tid] = ST[(size_t)r1*512 + tid];
      __syncthreads();
      if (tid < 400) {
        int row = tid / 200, rem = tid % 200, qi = rem >> 3, ks = rem & 7;
        const float* u2r = U2 + qi*512 + ks*64;
        const float* sl = &st_l[row][ks*64];
        float acc = 0.f;
        for (int j2 = 0; j2 < 64; ++j2) acc = fmaf(sl[j2], u2r[j2], acc);
        qp[row][qi][ks] = acc;
      }
      __syncthreads();
      if (tid < 50) {
        int row = tid / 25, qi = tid % 25;
        float s = B2[qi];
        for (int ks = 0; ks < 8; ++ks) s += qp[row][qi][ks];
        qv[row][qi] = s;
      }
      __syncthreads();
      if (tid < 50) {
        int row = tid / 25, qi = tid % 25;
        float m = qv[row][0];
        for (int i2 = 1; i2 < 25; ++i2) m = fmaxf(m, qv[row][i2]);
        float s = 0.f;
        for (int i2 = 0; i2 < 25; ++i2) s += expf(qv[row][i2] - m);
        float a = expf(qv[row][qi] - m) / s;
        al2[row][qi] = a;
        out_alpha[((size_t)t*B_ + (r0+row))*Q_ + qi] = a;
      }
      __syncthreads();
      if (tid < 150) {
        int row = tid / 75, k = tid % 75;
        xg_l[row][k] = f.inputs[(size_t)(r0+row)*T_*IN_ + (size_t)t*IN_ + k] * al2[row][k/3];
      }
      __syncthreads();
      float ga0=0,ga1=0,ga2=0,ga3=0, gb0=0,gb1=0,gb2=0,gb3=0;
      for (int k = 0; k < 75; ++k) {
        ushort4 w = W1T[(size_t)k*512 + tid];
        float w0=bfu(w.x), w1=bfu(w.y), w2=bfu(w.z), w3=bfu(w.w);
        float x0 = xg_l[0][k], x1 = xg_l[1][k];
        ga0=fmaf(x0,w0,ga0); ga1=fmaf(x0,w1,ga1); ga2=fmaf(x0,w2,ga2); ga3=fmaf(x0,w3,ga3);
        gb0=fmaf(x1,w0,gb0); gb1=fmaf(x1,w1,gb1); gb2=fmaf(x1,w2,gb2); gb3=fmaf(x1,w3,gb3);
      }
      ushort4 gh0 = G1H[(size_t)r0*512 + tid];
      ushort4 gh1 = G1H[(size_t)r1*512 + tid];
      {
        float i1 = sigm(ga0+bfu(gh0.x)), f1 = sigm(ga1+bfu(gh0.y));
        float g1 = tanhf(ga2+bfu(gh0.z)), o1 = sigm(ga3+bfu(gh0.w));
        c1a = f1*c1a + i1*g1;
        float be = BETA[(size_t)r0*512 + tid];
        float h1g = o1*tanhf(c1a) * be;
        H1[(size_t)tid*128 + r0] = h1g;
        out_beta[((size_t)t*B_ + r0)*H_ + tid] = be;
        if (t == T_-1) h1l[0][tid] = h1g;
      }
      {
        float i1 = sigm(gb0+bfu(gh1.x)), f1 = sigm(gb1+bfu(gh1.y));
        float g1 = tanhf(gb2+bfu(gh1.z)), o1 = sigm(gb3+bfu(gh1.w));
        c1b = f1*c1b + i1*g1;
        float be = BETA[(size_t)r1*512 + tid];
        float h1g = o1*tanhf(c1b) * be;
        H1[(size_t)tid*128 + r1] = h1g;
        out_beta[((size_t)t*B_ + r1)*H_ + tid] = be;
        if (t == T_-1) h1l[1][tid] = h1g;
      }
    }
    __threadfence();
    grid.sync();
  }

  // ---- epilogue: logits + log_softmax from final gated h1 ----
  if (bid < 64) {
    const int r0 = 2*bid;
    __syncthreads();
    if (tid < 480) {
      int row = tid / 240, rem = tid % 240, ci = rem >> 2, ks = rem & 3;
      const float* fr = f.fc_w + ci*512 + ks*128;
      const float* hr = &h1l[row][ks*128];
      float acc = 0.f;
      for (int j2 = 0; j2 < 128; ++j2) acc = fmaf(hr[j2], fr[j2], acc);
      lgp[row][ci][ks] = acc;
    }
    __syncthreads();
    if (tid < 120) {
      int row = tid / 60, ci = tid % 60;
      lg[row][ci] = f.fc_b[ci] + lgp[row][ci][0] + lgp[row][ci][1] + lgp[row][ci][2] + lgp[row][ci][3];
    }
    __syncthreads();
    if (tid < 120) {
      int row = tid / 60, ci = tid % 60;
      float m = lg[row][0];
      for (int i2 = 1; i2 < 60; ++i2) m = fmaxf(m, lg[row][i2]);
      float s = 0.f;
      for (int i2 = 0; i2 < 60; ++i2) s += expf(lg[row][i2] - m);
      out_logp[(size_t)(r0+row)*C_ + ci] = lg[row][ci] - m - logf(s);
    }
  }
}

extern "C" void kernel_launch(void* const* d_in, const int* in_sizes, int n_in,
                              void* d_out, int out_size, void* d_ws, size_t ws_size,
                              hipStream_t stream) {
  if (ws_size < WS_BYTES) return;  // fail loudly (output stays poisoned)

  Full f;
  f.inputs = (const float*)d_in[0];
  f.Wih_t = (const float*)d_in[2];  f.Whh_t = (const float*)d_in[3];
  f.bih_t = (const float*)d_in[4];  f.bhh_t = (const float*)d_in[5];
  f.Wih_s = (const float*)d_in[6];  f.Whh_s = (const float*)d_in[7];
  f.bih_s = (const float*)d_in[8];  f.bhh_s = (const float*)d_in[9];
  f.Wih_1 = (const float*)d_in[10]; f.Whh_1 = (const float*)d_in[11];
  f.bih_1 = (const float*)d_in[12]; f.bhh_1 = (const float*)d_in[13];
  f.fc_w  = (const float*)d_in[14]; f.fc_b  = (const float*)d_in[15];
  f.fct_w = (const float*)d_in[16]; f.fct_b = (const float*)d_in[17];
  f.fc1_w = (const float*)d_in[18]; f.fc1_b = (const float*)d_in[19];
  f.fc2_w = (const float*)d_in[20]; f.fc2_b = (const float*)d_in[21];
  f.W_x_t = (const float*)d_in[22]; f.W_h_t = (const float*)d_in[23];
  f.b_t   = (const float*)d_in[24];
  f.W_x_s = (const float*)d_in[25]; f.W_h_s = (const float*)d_in[26];
  f.U_s   = (const float*)d_in[27]; f.b_s   = (const float*)d_in[28];
  f.b_us  = (const float*)d_in[29];
  f.ws = (char*)d_ws;
  f.out = (float*)d_out;

  hipLaunchKernelGGL(prep_pack, dim3(2048), dim3(256), 0, stream, f);
  hipLaunchKernelGGL(prep_state, dim3(128), dim3(512), 0, stream, f);

  void* args[] = { &f };
  hipLaunchCooperativeKernel((void*)scan2, dim3(256), dim3(512), args, 0, stream);
}

// Round 3
// 15677.209 us; speedup vs baseline: 3.1921x; 1.9704x over previous
//
#include <hip/hip_runtime.h>
#include <math.h>

#define B_ 128
#define T_ 128
#define IN_ 75
#define H_ 512
#define C_ 60
#define Q_ 25

// ---------------- workspace layout (bytes) ----------------
constexpr size_t OFF_WXTP = 0;         // uint4 [ug][k2] bf16 pairs {W_x_t,W_h_t,W_x_s,W_h_s} (lo=k,hi=k+1)
constexpr size_t OFF_WIHP = 2097152;   // uint4 [ug][k]  bf16 {it|ft, gt|ot, is|fs, gs|os}
constexpr size_t OFF_FTP  = 2711552;   // uint  [ug][k]  bf16 {fct|fc1}
constexpr size_t OFF_W1P  = 2865152;   // uint2 [ug][k]  bf16 {i1|f1, g1|o1}
constexpr size_t OFF_U2   = 3172352;   // float [25][512]  (U_s @ fc2_w.T)
constexpr size_t OFF_B2   = 3223552;   // float [32]
constexpr size_t OFF_SPA  = 3223680;   // float4 [k=unit][bg] {h_t,h_s,tmp1,tmp2}
constexpr size_t OFF_H1   = 4272256;   // float2 [k2][bg] {h1(2k2),h1(2k2+1)}
constexpr size_t OFF_ST   = 4534400;   // float [b][j]
constexpr size_t OFF_AL   = 4796544;   // float [b][25]
constexpr size_t OFF_CTR  = 4809344;   // unsigned barrier counter
constexpr size_t WS_BYTES = 4809728;

struct Full {
  const float* inputs;
  const float* Wih_t; const float* Whh_t; const float* bih_t; const float* bhh_t;
  const float* Wih_s; const float* Whh_s; const float* bih_s; const float* bhh_s;
  const float* Wih_1; const float* Whh_1; const float* bih_1; const float* bhh_1;
  const float* fc_w;  const float* fc_b;
  const float* fct_w; const float* fct_b;
  const float* fc1_w; const float* fc1_b;
  const float* fc2_w; const float* fc2_b;
  const float* W_x_t; const float* W_h_t; const float* b_t;
  const float* W_x_s; const float* W_h_s; const float* U_s; const float* b_s; const float* b_us;
  char* ws; float* out;
};

__device__ __forceinline__ float sigm(float v) { return 1.f / (1.f + expf(-v)); }
__device__ __forceinline__ float blo(unsigned d) { return __uint_as_float(d << 16); }
__device__ __forceinline__ float bhi(unsigned d) { return __uint_as_float(d & 0xffff0000u); }
__device__ __forceinline__ unsigned short tob(float f) {
  unsigned u = __float_as_uint(f);
  return (unsigned short)((u + 0x7fffu + ((u >> 16) & 1u)) >> 16);
}
__device__ __forceinline__ unsigned pack2(float lo, float hi) {
  return (unsigned)tob(lo) | ((unsigned)tob(hi) << 16);
}

// grid barrier: release-add (writes back L2), relaxed spin, acquire-load (invalidates L2)
__device__ __forceinline__ void gbar(unsigned* ctr, unsigned target) {
  __syncthreads();
  if (threadIdx.x == 0) {
    __hip_atomic_fetch_add(ctr, 1u, __ATOMIC_RELEASE, __HIP_MEMORY_SCOPE_AGENT);
    while (__hip_atomic_load(ctr, __ATOMIC_RELAXED, __HIP_MEMORY_SCOPE_AGENT) < target)
      __builtin_amdgcn_s_sleep(1);
  }
  __syncthreads();
  (void)__hip_atomic_load(ctr, __ATOMIC_ACQUIRE, __HIP_MEMORY_SCOPE_AGENT);
}

// ---------------- prep: pack weights ----------------
__global__ void prep_pack(Full f) {
  uint4* WXTP = (uint4*)(f.ws + OFF_WXTP);
  uint4* WIHP = (uint4*)(f.ws + OFF_WIHP);
  unsigned* FTP = (unsigned*)(f.ws + OFF_FTP);
  uint2* W1P = (uint2*)(f.ws + OFF_W1P);
  float* U2 = (float*)(f.ws + OFF_U2);
  float* B2 = (float*)(f.ws + OFF_B2);
  if (blockIdx.x == 0 && threadIdx.x == 0) *(unsigned*)(f.ws + OFF_CTR) = 0;

  const size_t N1 = (size_t)512 * 256;   // WXTP (ug,k2)
  const size_t N2 = (size_t)512 * 75;    // WIHP
  const size_t N3 = (size_t)512 * 75;    // FTP
  const size_t N4 = (size_t)512 * 75;    // W1P
  const size_t N5 = (size_t)25 * 512;    // U2
  const size_t N6 = 25;                  // B2
  const size_t TOT = N1 + N2 + N3 + N4 + N5 + N6;
  for (size_t i = (size_t)blockIdx.x * blockDim.x + threadIdx.x; i < TOT;
       i += (size_t)gridDim.x * blockDim.x) {
    if (i < N1) {
      size_t ug = i >> 8, k2 = i & 255; size_t k = k2 * 2;
      uint4 v;
      v.x = pack2(f.W_x_t[k * 512 + ug], f.W_x_t[(k + 1) * 512 + ug]);
      v.y = pack2(f.W_h_t[k * 512 + ug], f.W_h_t[(k + 1) * 512 + ug]);
      v.z = pack2(f.W_x_s[k * 512 + ug], f.W_x_s[(k + 1) * 512 + ug]);
      v.w = pack2(f.W_h_s[k * 512 + ug], f.W_h_s[(k + 1) * 512 + ug]);
      WXTP[ug * 256 + k2] = v;
    } else if (i < N1 + N2) {
      size_t j = i - N1; size_t ug = j / 75, k = j % 75;
      uint4 v;
      v.x = pack2(f.Wih_t[ug * 75 + k],          f.Wih_t[(512 + ug) * 75 + k]);
      v.y = pack2(f.Wih_t[(1024 + ug) * 75 + k], f.Wih_t[(1536 + ug) * 75 + k]);
      v.z = pack2(f.Wih_s[ug * 75 + k],          f.Wih_s[(512 + ug) * 75 + k]);
      v.w = pack2(f.Wih_s[(1024 + ug) * 75 + k], f.Wih_s[(1536 + ug) * 75 + k]);
      WIHP[ug * 75 + k] = v;
    } else if (i < N1 + N2 + N3) {
      size_t j = i - N1 - N2; size_t ug = j / 75, k = j % 75;
      FTP[ug * 75 + k] = pack2(f.fct_w[ug * 75 + k], f.fc1_w[ug * 75 + k]);
    } else if (i < N1 + N2 + N3 + N4) {
      size_t j = i - N1 - N2 - N3; size_t ug = j / 75, k = j % 75;
      uint2 v;
      v.x = pack2(f.Wih_1[ug * 75 + k],          f.Wih_1[(512 + ug) * 75 + k]);
      v.y = pack2(f.Wih_1[(1024 + ug) * 75 + k], f.Wih_1[(1536 + ug) * 75 + k]);
      W1P[ug * 75 + k] = v;
    } else if (i < N1 + N2 + N3 + N4 + N5) {
      size_t j = i - N1 - N2 - N3 - N4; size_t qi = j >> 9, col = j & 511;
      float acc = 0.f;
      for (int n = 0; n < 512; ++n) acc = fmaf(f.U_s[col * 512 + n], f.fc2_w[qi * 512 + n], acc);
      U2[qi * 512 + col] = acc;
    } else {
      size_t qi = i - N1 - N2 - N3 - N4 - N5;
      float acc = f.fc2_b[qi];
      for (int n = 0; n < 512; ++n) acc = fmaf(f.b_us[n], f.fc2_w[qi * 512 + n], acc);
      B2[qi] = acc;
    }
  }
}

// ---------------- prep: initial state ----------------
__global__ __launch_bounds__(512) void prep_state(Full f) {
  const int b = blockIdx.x, j = threadIdx.x;
  __shared__ float x0[77];
  if (j < IN_) x0[j] = f.inputs[(size_t)b * T_ * IN_ + j];
  __syncthreads();
  float t1 = f.fct_b[j], t2 = f.fc1_b[j];
  for (int k = 0; k < IN_; ++k) {
    t1 = fmaf(x0[k], f.fct_w[j * IN_ + k], t1);
    t2 = fmaf(x0[k], f.fc1_w[j * IN_ + k], t2);
  }
  float4* SPA4 = (float4*)(f.ws + OFF_SPA);
  SPA4[(size_t)j * 128 + b] = make_float4(0.f, 0.f, t1, t2);
  ((float*)(f.ws + OFF_H1))[(((size_t)(j >> 1)) * 128 + b) * 2 + (j & 1)] = 0.f;
}

// ---------------- main persistent scan ----------------
__global__ __launch_bounds__(512, 1) void scan3(Full f) {
  const int tid = threadIdx.x, bid = blockIdx.x;
  const int h = tid >> 8;                 // k-half
  const int w = (tid >> 6) & 3, l = tid & 63;
  const int u = l & 3;                    // local unit 0..3
  const int bLrow = w * 16 + (l >> 2);    // local row 0..63
  const int bb = bid >> 7, bj = bid & 127;
  const int ug = bj * 4 + u;              // global unit
  const int bg = bb * 64 + bLrow;         // global batch row
  const int pid = (tid & 255);            // (u,bLrow) pair id

  char* wsb = f.ws;
  const uint4* WXTP = (const uint4*)(wsb + OFF_WXTP);
  const uint4* WIHP = (const uint4*)(wsb + OFF_WIHP);
  const unsigned* FTP = (const unsigned*)(wsb + OFF_FTP);
  const uint2* W1P = (const uint2*)(wsb + OFF_W1P);
  const float* U2 = (const float*)(wsb + OFF_U2);
  const float* B2 = (const float*)(wsb + OFF_B2);
  float4* SPA4 = (float4*)(wsb + OFF_SPA);
  float* H1f = (float*)(wsb + OFF_H1);
  const float2* H1p2 = (const float2*)(wsb + OFF_H1);
  float* ST = (float*)(wsb + OFF_ST);
  float* ALPHA = (float*)(wsb + OFF_AL);
  unsigned* CTR = (unsigned*)(wsb + OFF_CTR);

  float* out_logp = f.out;
  float* out_alpha = f.out + B_ * C_;
  float* out_beta = f.out + B_ * C_ + (size_t)T_ * B_ * Q_;

  // ---- LDS ----
  __shared__ float WhhL[3][512][4][4];    // [cell][k][u][gate] fp32   98304B
  __shared__ uint4 WXL[256][4];           // [k2][u]                   16384B
  __shared__ uint4 WihL[75][4];           // [k][u]                     4800B
  __shared__ unsigned FTL[75][4];         //                            1200B
  __shared__ uint2 W1L[75][4];            //                            2400B
  __shared__ unsigned short xcur[64][76]; // bf16 x rows                9728B
  __shared__ float redU[4352];            // 256*17 reduce / B scratch 17408B
  __shared__ float alphaL[64][26];        //                            6656B

  // ---- stage weights into LDS (once) ----
  for (int c = 0; c < 3; ++c) {
    const float* W = (c == 0) ? f.Whh_t : (c == 1) ? f.Whh_s : f.Whh_1;
    for (int i = tid; i < 8192; i += 512) {
      int k = i & 511, gu = i >> 9, g = gu >> 2, uu = gu & 3;
      WhhL[c][k][uu][g] = W[((size_t)(g * 512 + bj * 4 + uu)) * 512 + k];
    }
  }
  for (int i = tid; i < 1024; i += 512) {
    int k2 = i >> 2, uu = i & 3;
    WXL[k2][uu] = WXTP[(size_t)(bj * 4 + uu) * 256 + k2];
  }
  for (int i = tid; i < 300; i += 512) {
    int k = i >> 2, uu = i & 3;
    WihL[k][uu] = WIHP[(size_t)(bj * 4 + uu) * 75 + k];
    FTL[k][uu] = FTP[(size_t)(bj * 4 + uu) * 75 + k];
    W1L[k][uu] = W1P[(size_t)(bj * 4 + uu) * 75 + k];
  }
  // stage x(t=0)
  for (int i = tid; i < 64 * IN_; i += 512) {
    int r = i / IN_, k = i - r * IN_;
    xcur[r][k] = tob(f.inputs[((size_t)(bb * 64 + r) * T_) * IN_ + k]);
  }
  __syncthreads();

  // biases (indexed by ug)
  float btb0 = f.bih_t[ug] + f.bhh_t[ug];
  float btb1 = f.bih_t[512 + ug] + f.bhh_t[512 + ug];
  float btb2 = f.bih_t[1024 + ug] + f.bhh_t[1024 + ug];
  float btb3 = f.bih_t[1536 + ug] + f.bhh_t[1536 + ug];
  float bsb0 = f.bih_s[ug] + f.bhh_s[ug];
  float bsb1 = f.bih_s[512 + ug] + f.bhh_s[512 + ug];
  float bsb2 = f.bih_s[1024 + ug] + f.bhh_s[1024 + ug];
  float bsb3 = f.bih_s[1536 + ug] + f.bhh_s[1536 + ug];
  float b1b0 = f.bih_1[ug] + f.bhh_1[ug];
  float b1b1 = f.bih_1[512 + ug] + f.bhh_1[512 + ug];
  float b1b2 = f.bih_1[1024 + ug] + f.bhh_1[1024 + ug];
  float b1b3 = f.bih_1[1536 + ug] + f.bhh_1[1536 + ug];
  const float bB = f.b_s[ug] + f.b_t[ug];
  const float bS = f.b_s[ug];
  const float bT1 = f.fct_b[ug], bT2 = f.fc1_b[ug];

  float c_t = 0.f, c_s = 0.f, c1 = 0.f;
  unsigned bcount = 0;

  for (int t = 0; t < T_; ++t) {
    // ================= phase A: all k-sums vs prev state =================
    float at0 = 0, at1 = 0, at2 = 0, at3 = 0;
    float as0 = 0, as1 = 0, as2 = 0, as3 = 0;
    float g10 = 0, g11 = 0, g12 = 0, g13 = 0;
    float aB = 0, aS = 0;
    const int kbase = h * 256;
#pragma unroll 2
    for (int kk = kbase; kk < kbase + 256; kk += 2) {
      const float4 s0 = SPA4[(size_t)kk * 128 + bg];
      const float4 s1 = SPA4[(size_t)(kk + 1) * 128 + bg];
      const float2 h1p = H1p2[(size_t)(kk >> 1) * 128 + bg];
      const float4 wt0 = *(const float4*)WhhL[0][kk][u];
      const float4 wt1 = *(const float4*)WhhL[0][kk + 1][u];
      const float4 wv0 = *(const float4*)WhhL[1][kk][u];
      const float4 wv1 = *(const float4*)WhhL[1][kk + 1][u];
      const float4 w10 = *(const float4*)WhhL[2][kk][u];
      const float4 w11 = *(const float4*)WhhL[2][kk + 1][u];
      const uint4 wx = WXL[kk >> 1][u];
      at0 = fmaf(s0.x, wt0.x, at0); at1 = fmaf(s0.x, wt0.y, at1);
      at2 = fmaf(s0.x, wt0.z, at2); at3 = fmaf(s0.x, wt0.w, at3);
      at0 = fmaf(s1.x, wt1.x, at0); at1 = fmaf(s1.x, wt1.y, at1);
      at2 = fmaf(s1.x, wt1.z, at2); at3 = fmaf(s1.x, wt1.w, at3);
      as0 = fmaf(s0.y, wv0.x, as0); as1 = fmaf(s0.y, wv0.y, as1);
      as2 = fmaf(s0.y, wv0.z, as2); as3 = fmaf(s0.y, wv0.w, as3);
      as0 = fmaf(s1.y, wv1.x, as0); as1 = fmaf(s1.y, wv1.y, as1);
      as2 = fmaf(s1.y, wv1.z, as2); as3 = fmaf(s1.y, wv1.w, as3);
      g10 = fmaf(h1p.x, w10.x, g10); g11 = fmaf(h1p.x, w10.y, g11);
      g12 = fmaf(h1p.x, w10.z, g12); g13 = fmaf(h1p.x, w10.w, g13);
      g10 = fmaf(h1p.y, w11.x, g10); g11 = fmaf(h1p.y, w11.y, g11);
      g12 = fmaf(h1p.y, w11.z, g12); g13 = fmaf(h1p.y, w11.w, g13);
      aB = fmaf(s0.z, blo(wx.x), aB); aB = fmaf(s0.x, blo(wx.y), aB);
      aB = fmaf(s1.z, bhi(wx.x), aB); aB = fmaf(s1.x, bhi(wx.y), aB);
      aS = fmaf(s0.w, blo(wx.z), aS); aS = fmaf(s0.y, blo(wx.w), aS);
      aS = fmaf(s1.w, bhi(wx.z), aS); aS = fmaf(s1.y, bhi(wx.w), aS);
    }
    // x-part of gates_t / gates_s
    {
      const int kx0 = h ? 38 : 0, kx1 = h ? 75 : 38;
      for (int k = kx0; k < kx1; ++k) {
        const float xv = __uint_as_float((unsigned)xcur[bLrow][k] << 16);
        const uint4 wi = WihL[k][u];
        at0 = fmaf(xv, blo(wi.x), at0); at1 = fmaf(xv, bhi(wi.x), at1);
        at2 = fmaf(xv, blo(wi.y), at2); at3 = fmaf(xv, bhi(wi.y), at3);
        as0 = fmaf(xv, blo(wi.z), as0); as1 = fmaf(xv, bhi(wi.z), as1);
        as2 = fmaf(xv, blo(wi.w), as2); as3 = fmaf(xv, bhi(wi.w), as3);
      }
    }
    if (h) {
      float* rp = &redU[pid * 17];
      rp[0] = at0; rp[1] = at1; rp[2] = at2; rp[3] = at3;
      rp[4] = as0; rp[5] = as1; rp[6] = as2; rp[7] = as3;
      rp[8] = g10; rp[9] = g11; rp[10] = g12; rp[11] = g13;
      rp[12] = aB; rp[13] = aS;
    }
    __syncthreads();
    float htn = 0.f, hsn = 0.f, stv = 0.f, betav = 0.f;
    float gh0 = 0.f, gh1 = 0.f, gh2 = 0.f, gh3 = 0.f;
    if (!h) {
      const float* rp = &redU[pid * 17];
      at0 += rp[0]; at1 += rp[1]; at2 += rp[2]; at3 += rp[3];
      as0 += rp[4]; as1 += rp[5]; as2 += rp[6]; as3 += rp[7];
      g10 += rp[8]; g11 += rp[9]; g12 += rp[10]; g13 += rp[11];
      aB += rp[12]; aS += rp[13];
      const float it = sigm(at0 + btb0), ft = sigm(at1 + btb1);
      const float gt = tanhf(at2 + btb2), ot = sigm(at3 + btb3);
      c_t = ft * c_t + it * gt; htn = ot * tanhf(c_t);
      const float is = sigm(as0 + bsb0), fs = sigm(as1 + bsb1);
      const float gs = tanhf(as2 + bsb2), os = sigm(as3 + bsb3);
      c_s = fs * c_s + is * gs; hsn = os * tanhf(c_s);
      stv = tanhf(aS + bS);
      betav = fmaxf(aB + bB, 0.f);
      gh0 = g10 + b1b0; gh1 = g11 + b1b1; gh2 = g12 + b1b2; gh3 = g13 + b1b3;
      ST[(size_t)bg * 512 + ug] = stv;
    }
    gbar(CTR, (++bcount) * 256);

    // ================= phase B: alpha softmax (128 blocks, 1 row each) =================
    if (bid < 128) {
      const int r = bid;
      float* stl = redU;            // [0..511]
      float* qp = redU + 512;       // [25*16]
      float* qv = redU + 1024;      // [25]
      stl[tid] = ST[(size_t)r * 512 + tid];
      __syncthreads();
      if (tid < 400) {
        const int qi = tid >> 4, ks = tid & 15;
        const float* u2p = U2 + (size_t)qi * 512 + ks * 32;
        const float* sp = stl + ks * 32;
        float acc = 0.f;
        for (int j = 0; j < 32; j += 4) {
          const float4 uv = *(const float4*)(u2p + j);
          const float4 sv = *(const float4*)(sp + j);
          acc += sv.x * uv.x + sv.y * uv.y + sv.z * uv.z + sv.w * uv.w;
        }
        qp[qi * 16 + ks] = acc;
      }
      __syncthreads();
      if (tid < 25) {
        float s = B2[tid];
        for (int j = 0; j < 16; ++j) s += qp[tid * 16 + j];
        qv[tid] = s;
      }
      __syncthreads();
      if (tid < 25) {
        float m = qv[0];
        for (int i2 = 1; i2 < 25; ++i2) m = fmaxf(m, qv[i2]);
        float s = 0.f;
        for (int i2 = 0; i2 < 25; ++i2) s += expf(qv[i2] - m);
        const float a = expf(qv[tid] - m) / s;
        ALPHA[(size_t)r * 25 + tid] = a;
        out_alpha[((size_t)t * B_ + r) * Q_ + tid] = a;
      }
    }
    gbar(CTR, (++bcount) * 256);

    // ================= phase C: cell1 + h1*beta + tmp-next =================
    for (int i = tid; i < 64 * 25; i += 512) {
      const int r = i / 25, q = i - r * 25;
      alphaL[r][q] = ALPHA[(size_t)(bb * 64 + r) * 25 + q];
    }
    __syncthreads();
    float cx0 = 0, cx1 = 0, cx2 = 0, cx3 = 0;
    {
      const int q0 = h ? 13 : 0, q1 = h ? 25 : 13;
      for (int q = q0; q < q1; ++q) {
        const float av = alphaL[bLrow][q];
#pragma unroll
        for (int j = 0; j < 3; ++j) {
          const int k = q * 3 + j;
          const float xg = __uint_as_float((unsigned)xcur[bLrow][k] << 16) * av;
          const uint2 w1v = W1L[k][u];
          cx0 = fmaf(xg, blo(w1v.x), cx0); cx1 = fmaf(xg, bhi(w1v.x), cx1);
          cx2 = fmaf(xg, blo(w1v.y), cx2); cx3 = fmaf(xg, bhi(w1v.y), cx3);
        }
      }
    }
    if (h) {
      float* rp = &redU[pid * 17];
      rp[0] = cx0; rp[1] = cx1; rp[2] = cx2; rp[3] = cx3;
    }
    __syncthreads();
    // reload xcur <- x(t+1)
    if (t < T_ - 1) {
      for (int i = tid; i < 64 * IN_; i += 512) {
        const int r = i / IN_, k = i - r * IN_;
        xcur[r][k] = tob(f.inputs[((size_t)(bb * 64 + r) * T_ + (t + 1)) * IN_ + k]);
      }
    }
    __syncthreads();
    float aT1 = 0.f, aT2 = 0.f;
    if (t < T_ - 1) {
      const int kx0 = h ? 38 : 0, kx1 = h ? 75 : 38;
      for (int k = kx0; k < kx1; ++k) {
        const float xn = __uint_as_float((unsigned)xcur[bLrow][k] << 16);
        const unsigned ftv = FTL[k][u];
        aT1 = fmaf(xn, blo(ftv), aT1);
        aT2 = fmaf(xn, bhi(ftv), aT2);
      }
    }
    if (h) {
      float* rp = &redU[pid * 17];
      rp[14] = aT1; rp[15] = aT2;
    }
    __syncthreads();
    if (!h) {
      const float* rp = &redU[pid * 17];
      cx0 += rp[0]; cx1 += rp[1]; cx2 += rp[2]; cx3 += rp[3];
      const float t1n = aT1 + rp[14] + bT1;
      const float t2n = aT2 + rp[15] + bT2;
      const float i1 = sigm(cx0 + gh0), f1 = sigm(cx1 + gh1);
      const float gg = tanhf(cx2 + gh2), o1 = sigm(cx3 + gh3);
      c1 = f1 * c1 + i1 * gg;
      const float h1g = o1 * tanhf(c1) * betav;
      H1f[(((size_t)(ug >> 1)) * 128 + bg) * 2 + (ug & 1)] = h1g;
      if (t < T_ - 1) SPA4[(size_t)ug * 128 + bg] = make_float4(htn, hsn, t1n, t2n);
      out_beta[((size_t)t * B_ + bg) * H_ + ug] = betav;
    }
    gbar(CTR, (++bcount) * 256);
  }

  // ================= epilogue: logits + log_softmax =================
  if (bid < 128) {
    const int r = bid;
    redU[tid] = H1f[(((size_t)(tid >> 1)) * 128 + r) * 2 + (tid & 1)];
    __syncthreads();
    if (tid < 480) {
      const int ci = tid >> 3, ks = tid & 7;
      const float* fr = f.fc_w + (size_t)ci * 512 + ks * 64;
      const float* hr = redU + ks * 64;
      float acc = 0.f;
      for (int j = 0; j < 64; j += 4) {
        const float4 fv = *(const float4*)(fr + j);
        const float4 hv = *(const float4*)(hr + j);
        acc += hv.x * fv.x + hv.y * fv.y + hv.z * fv.z + hv.w * fv.w;
      }
      redU[512 + ci * 8 + ks] = acc;
    }
    __syncthreads();
    if (tid < 60) {
      float s = f.fc_b[tid];
      for (int j = 0; j < 8; ++j) s += redU[512 + tid * 8 + j];
      redU[1024 + tid] = s;
    }
    __syncthreads();
    if (tid < 60) {
      float m = redU[1024];
      for (int i2 = 1; i2 < 60; ++i2) m = fmaxf(m, redU[1024 + i2]);
      float ssum = 0.f;
      for (int i2 = 0; i2 < 60; ++i2) ssum += expf(redU[1024 + i2] - m);
      out_logp[(size_t)r * C_ + tid] = redU[1024 + tid] - m - logf(ssum);
    }
  }
}

extern "C" void kernel_launch(void* const* d_in, const int* in_sizes, int n_in,
                              void* d_out, int out_size, void* d_ws, size_t ws_size,
                              hipStream_t stream) {
  if (ws_size < WS_BYTES) return;  // fail loudly (output stays poisoned)

  Full f;
  f.inputs = (const float*)d_in[0];
  f.Wih_t = (const float*)d_in[2];  f.Whh_t = (const float*)d_in[3];
  f.bih_t = (const float*)d_in[4];  f.bhh_t = (const float*)d_in[5];
  f.Wih_s = (const float*)d_in[6];  f.Whh_s = (const float*)d_in[7];
  f.bih_s = (const float*)d_in[8];  f.bhh_s = (const float*)d_in[9];
  f.Wih_1 = (const float*)d_in[10]; f.Whh_1 = (const float*)d_in[11];
  f.bih_1 = (const float*)d_in[12]; f.bhh_1 = (const float*)d_in[13];
  f.fc_w  = (const float*)d_in[14]; f.fc_b  = (const float*)d_in[15];
  f.fct_w = (const float*)d_in[16]; f.fct_b = (const float*)d_in[17];
  f.fc1_w = (const float*)d_in[18]; f.fc1_b = (const float*)d_in[19];
  f.fc2_w = (const float*)d_in[20]; f.fc2_b = (const float*)d_in[21];
  f.W_x_t = (const float*)d_in[22]; f.W_h_t = (const float*)d_in[23];
  f.b_t   = (const float*)d_in[24];
  f.W_x_s = (const float*)d_in[25]; f.W_h_s = (const float*)d_in[26];
  f.U_s   = (const float*)d_in[27]; f.b_s   = (const float*)d_in[28];
  f.b_us  = (const float*)d_in[29];
  f.ws = (char*)d_ws;
  f.out = (float*)d_out;

  hipLaunchKernelGGL(prep_pack, dim3(1024), dim3(256), 0, stream, f);
  hipLaunchKernelGGL(prep_state, dim3(128), dim3(512), 0, stream, f);

  void* args[] = { &f };
  hipLaunchCooperativeKernel((void*)scan3, dim3(256), dim3(512), args, 0, stream);
}